// Round 4
// baseline (1286.400 us; speedup 1.0000x reference)
//
#include <hip/hip_runtime.h>
#include <math.h>

// ParityPonderGRU — all-MFMA split-fp16; fused halt partials; 2 blocks/CU step GEMM.
// B=2048, E=512, H=1024, 20 ponder steps.
// ws: gx f32[B*3H] | Whi/Wlo f16[3H*H] | hAhi hAlo hBhi hBlo f16[B*H] |
//     part_lam f32[32*B] | part_out f32[32*B] | states f32[4*B]  (~55.1 MB)
// (W_ih / x fp16 splits transiently live in hA* / hB* before init_h0.)

#define B_N 2048
#define E_N 512
#define H_N 1024
#define G3  3072
#define NSTEPS 20
#define BK 32
#define NT_H (H_N / BK)   // 32 K-steps (step GEMM)
#define NT_E (E_N / BK)   // 16 K-steps (gx GEMM)
#define NCB  (H_N / 32)   // 32 col-blocks -> halt partials

typedef __attribute__((ext_vector_type(8))) _Float16 f16x8;
typedef __attribute__((ext_vector_type(4))) _Float16 f16x4v;
typedef __attribute__((ext_vector_type(4))) float    f32x4;

#define GLDS(src, dst) \
  __builtin_amdgcn_global_load_lds( \
      (const __attribute__((address_space(1))) void*)(src), \
      (__attribute__((address_space(3))) void*)(dst), 16, 0, 0)

__device__ __forceinline__ float sigmoidf_(float x) { return 1.0f / (1.0f + expf(-x)); }

// ---------------- Fused step GEMM: gh = h @ W_hh^T (3-product split-fp16 MFMA)
// Block 128(B) x 32(H) x 3 gates; 4 waves 2x2; wave tile 64x16 per gate.
// LDS/buffer (halves): Ahi[0,4096) Alo[4096,8192) Bhi[8192,11264) Blo[11264,14336)
// = 28 KB/buffer, dbuf = 56 KB -> 2 blocks/CU (112 KB), 2 waves/SIMD.
// Epilogue also reduces per-row partial dots h.w_lam / h.w_out for the NEXT halt.
__global__ __launch_bounds__(256, 2)
void gemm_step_mfma(const _Float16* __restrict__ h_hi_in,  // [B,H]
                    const _Float16* __restrict__ h_lo_in,  // [B,H]
                    const _Float16* __restrict__ Whi,      // [3H,H]
                    const _Float16* __restrict__ Wlo,      // [3H,H]
                    const float* __restrict__ b_hh,        // [3H]
                    const float* __restrict__ gx,          // [B,3H]
                    const float* __restrict__ w_lam,
                    const float* __restrict__ w_out,
                    _Float16* __restrict__ h_hi_out,
                    _Float16* __restrict__ h_lo_out,
                    float* __restrict__ part_lam,          // [NCB*B]
                    float* __restrict__ part_out)          // [NCB*B]
{
  __shared__ _Float16 lds[2][14336];     // 57344 B
  __shared__ float pl_red[128][2], po_red[128][2];

  const int tid  = threadIdx.x;
  const int lane = tid & 63;
  const int wv   = tid >> 6;
  const int wr   = wv >> 1;
  const int wc   = wv & 1;
  const int row0 = blockIdx.y * 128;   // over B
  const int col0 = blockIdx.x * 32;    // over H
  const int cb   = blockIdx.x;

  // staging: 28 chunks of 1 KB (16 rows x 32 halves, lane-linear); wave owns 7
  const _Float16* srcp[7];
  int ldsoff[7];
  #pragma unroll
  for (int j = 0; j < 7; ++j) {
    const int c     = wv * 7 + j;
    const int seg   = (lane & 3) * 8;
    const int row16 = lane >> 2;
    const _Float16* s;
    if (c < 8) {
      s = h_hi_in + (size_t)(row0 + c * 16 + row16) * H_N + seg;
    } else if (c < 16) {
      s = h_lo_in + (size_t)(row0 + (c - 8) * 16 + row16) * H_N + seg;
    } else if (c < 22) {
      const int br = (c - 16) * 16 + row16;                 // 0..95
      s = Whi + (size_t)((br >> 5) * H_N + col0 + (br & 31)) * H_N + seg;
    } else {
      const int br = (c - 22) * 16 + row16;
      s = Wlo + (size_t)((br >> 5) * H_N + col0 + (br & 31)) * H_N + seg;
    }
    srcp[j]   = s;
    ldsoff[j] = c * 512;
  }

  f32x4 acc[3][4];
  #pragma unroll
  for (int g = 0; g < 3; ++g)
    #pragma unroll
    for (int mi = 0; mi < 4; ++mi)
      acc[g][mi] = (f32x4){0.f, 0.f, 0.f, 0.f};

  const int lrow = lane & 15;
  const int lk   = (lane >> 4) * 8;
  const int q    = lane >> 4;

  #pragma unroll
  for (int j = 0; j < 7; ++j) { GLDS(srcp[j], &lds[0][ldsoff[j]]); srcp[j] += BK; }
  __syncthreads();

  for (int t = 0; t < NT_H; ++t) {
    const int p = t & 1;
    if (t + 1 < NT_H) {
      #pragma unroll
      for (int j = 0; j < 7; ++j) { GLDS(srcp[j], &lds[p ^ 1][ldsoff[j]]); srcp[j] += BK; }
    }
    f16x8 ah[4], al[4];
    #pragma unroll
    for (int mi = 0; mi < 4; ++mi) {
      const int r = wr * 64 + mi * 16 + lrow;
      ah[mi] = *(const f16x8*)&lds[p][r * 32 + lk];
      al[mi] = *(const f16x8*)&lds[p][4096 + r * 32 + lk];
    }
    f16x8 bh[3], bl[3];
    #pragma unroll
    for (int g = 0; g < 3; ++g) {
      const int r = g * 32 + wc * 16 + lrow;
      bh[g] = *(const f16x8*)&lds[p][8192 + r * 32 + lk];
      bl[g] = *(const f16x8*)&lds[p][11264 + r * 32 + lk];
    }
    #pragma unroll
    for (int g = 0; g < 3; ++g)
      #pragma unroll
      for (int mi = 0; mi < 4; ++mi) {
        f32x4 c = acc[g][mi];
        c = __builtin_amdgcn_mfma_f32_16x16x32_f16(ah[mi], bh[g], c, 0, 0, 0);
        c = __builtin_amdgcn_mfma_f32_16x16x32_f16(ah[mi], bl[g], c, 0, 0, 0);
        c = __builtin_amdgcn_mfma_f32_16x16x32_f16(al[mi], bh[g], c, 0, 0, 0);
        acc[g][mi] = c;
      }
    __syncthreads();
  }

  // Epilogue: D frag col=lane&15 (output col n), row=(lane>>4)*4+r (batch m) [m89]
  const int n   = col0 + wc * 16 + lrow;
  const float bhr = b_hh[n];
  const float bhz = b_hh[H_N + n];
  const float bhn = b_hh[2 * H_N + n];
  const float wl  = w_lam[n];
  const float wo  = w_out[n];
  #pragma unroll
  for (int mi = 0; mi < 4; ++mi) {
    #pragma unroll
    for (int r = 0; r < 4; ++r) {
      const int m = row0 + wr * 64 + mi * 16 + q * 4 + r;
      const float gr = acc[0][mi][r] + bhr;
      const float gz = acc[1][mi][r] + bhz;
      const float gn = acc[2][mi][r] + bhn;
      const size_t gxb = (size_t)m * G3;
      const float rr = sigmoidf_(gx[gxb + n] + gr);
      const float zz = sigmoidf_(gx[gxb + H_N + n] + gz);
      const float nn = tanhf(gx[gxb + 2 * H_N + n] + rr * gn);
      const size_t hidx = (size_t)m * H_N + n;
      const float hold = (float)h_hi_in[hidx] + (float)h_lo_in[hidx];
      const float hf = (1.f - zz) * nn + zz * hold;
      const _Float16 hh = (_Float16)hf;
      h_hi_out[hidx] = hh;
      h_lo_out[hidx] = (_Float16)(hf - (float)hh);
      // partial dots over this block's 32 cols (16 via this wave's wc half)
      float pl = hf * wl;
      float po = hf * wo;
      #pragma unroll
      for (int mk = 1; mk < 16; mk <<= 1) {
        pl += __shfl_xor(pl, mk);
        po += __shfl_xor(po, mk);
      }
      if (lrow == 0) {
        pl_red[wr * 64 + mi * 16 + q * 4 + r][wc] = pl;
        po_red[wr * 64 + mi * 16 + q * 4 + r][wc] = po;
      }
    }
  }
  __syncthreads();
  if (tid < 128) {
    const int m = row0 + tid;
    part_lam[(size_t)cb * B_N + m] = pl_red[tid][0] + pl_red[tid][1];
    part_out[(size_t)cb * B_N + m] = po_red[tid][0] + po_red[tid][1];
  }
}

// ---------------- gx GEMM (MFMA): gx = x @ W_ih^T + b_ih -------------------
// Block 128(B) x 64(3H); 4 waves 2x2; wave tile 64x32; K=512.
// LDS/buffer: Ahi[0,4096) Alo[4096,8192) Bhi[8192,10240) Blo[10240,12288) = 24 KB.
__global__ __launch_bounds__(256, 3)
void gemm_gx_mfma(const _Float16* __restrict__ xhi,    // [B,E]
                  const _Float16* __restrict__ xlo,
                  const _Float16* __restrict__ Wihhi,  // [3H,E]
                  const _Float16* __restrict__ Wihlo,
                  const float* __restrict__ b_ih,
                  float* __restrict__ gx)              // [B,3H]
{
  __shared__ _Float16 lds[2][12288];   // 49152 B

  const int tid  = threadIdx.x;
  const int lane = tid & 63;
  const int wv   = tid >> 6;
  const int wr   = wv >> 1;
  const int wc   = wv & 1;
  const int row0 = blockIdx.y * 128;   // over B
  const int col0 = blockIdx.x * 64;    // over 3H

  const _Float16* srcp[6];
  int ldsoff[6];
  #pragma unroll
  for (int j = 0; j < 6; ++j) {
    const int c     = wv * 6 + j;
    const int seg   = (lane & 3) * 8;
    const int row16 = lane >> 2;
    const _Float16* s;
    if (c < 8)       s = xhi   + (size_t)(row0 + c * 16 + row16) * E_N + seg;
    else if (c < 16) s = xlo   + (size_t)(row0 + (c - 8) * 16 + row16) * E_N + seg;
    else if (c < 20) s = Wihhi + (size_t)(col0 + (c - 16) * 16 + row16) * E_N + seg;
    else             s = Wihlo + (size_t)(col0 + (c - 20) * 16 + row16) * E_N + seg;
    srcp[j]   = s;
    ldsoff[j] = c * 512;
  }

  f32x4 acc[4][2];
  #pragma unroll
  for (int mi = 0; mi < 4; ++mi)
    #pragma unroll
    for (int ni = 0; ni < 2; ++ni) acc[mi][ni] = (f32x4){0.f, 0.f, 0.f, 0.f};

  const int lrow = lane & 15;
  const int lk   = (lane >> 4) * 8;
  const int q    = lane >> 4;

  #pragma unroll
  for (int j = 0; j < 6; ++j) { GLDS(srcp[j], &lds[0][ldsoff[j]]); srcp[j] += BK; }
  __syncthreads();

  for (int t = 0; t < NT_E; ++t) {
    const int p = t & 1;
    if (t + 1 < NT_E) {
      #pragma unroll
      for (int j = 0; j < 6; ++j) { GLDS(srcp[j], &lds[p ^ 1][ldsoff[j]]); srcp[j] += BK; }
    }
    f16x8 ah[4], al[4];
    #pragma unroll
    for (int mi = 0; mi < 4; ++mi) {
      const int r = wr * 64 + mi * 16 + lrow;
      ah[mi] = *(const f16x8*)&lds[p][r * 32 + lk];
      al[mi] = *(const f16x8*)&lds[p][4096 + r * 32 + lk];
    }
    f16x8 bh[2], bl[2];
    #pragma unroll
    for (int ni = 0; ni < 2; ++ni) {
      const int r = wc * 32 + ni * 16 + lrow;
      bh[ni] = *(const f16x8*)&lds[p][8192 + r * 32 + lk];
      bl[ni] = *(const f16x8*)&lds[p][10240 + r * 32 + lk];
    }
    #pragma unroll
    for (int mi = 0; mi < 4; ++mi)
      #pragma unroll
      for (int ni = 0; ni < 2; ++ni) {
        f32x4 c = acc[mi][ni];
        c = __builtin_amdgcn_mfma_f32_16x16x32_f16(ah[mi], bh[ni], c, 0, 0, 0);
        c = __builtin_amdgcn_mfma_f32_16x16x32_f16(ah[mi], bl[ni], c, 0, 0, 0);
        c = __builtin_amdgcn_mfma_f32_16x16x32_f16(al[mi], bh[ni], c, 0, 0, 0);
        acc[mi][ni] = c;
      }
    __syncthreads();
  }

  #pragma unroll
  for (int mi = 0; mi < 4; ++mi) {
    #pragma unroll
    for (int ni = 0; ni < 2; ++ni) {
      const int n = col0 + wc * 32 + ni * 16 + lrow;
      const float bi = b_ih[n];
      #pragma unroll
      for (int r = 0; r < 4; ++r) {
        const int m = row0 + wr * 64 + mi * 16 + q * 4 + r;
        gx[(size_t)m * G3 + n] = acc[mi][ni][r] + bi;
      }
    }
  }
}

// ---------------- one-time: split fp32 -> fp16 hi/lo -----------------------
__global__ __launch_bounds__(256)
void split_f32_kernel(const float* __restrict__ src,
                      _Float16* __restrict__ hi, _Float16* __restrict__ lo)
{
  const size_t base = ((size_t)blockIdx.x * 256 + threadIdx.x) * 4;
  const float4 w = *(const float4*)&src[base];
  float s[4] = {w.x, w.y, w.z, w.w};
  f16x4v h4, l4;
  #pragma unroll
  for (int e = 0; e < 4; ++e) {
    const _Float16 h = (_Float16)s[e];
    h4[e] = h;
    l4[e] = (_Float16)(s[e] - (float)h);
  }
  *(f16x4v*)&hi[base] = h4;
  *(f16x4v*)&lo[base] = l4;
}

// ---------------- h0 = gru_cell(x, 0): gh = b_hh; init states --------------
__global__ __launch_bounds__(256)
void init_h0_kernel(const float* __restrict__ gx, const float* __restrict__ b_hh,
                    _Float16* __restrict__ h_hi, _Float16* __restrict__ h_lo,
                    float* __restrict__ states)
{
    const int idx = blockIdx.x * 256 + threadIdx.x;
    const int r = idx >> 10;
    const int c = idx & (H_N - 1);
    const float rr = sigmoidf_(gx[(size_t)r * G3 + c] + b_hh[c]);
    const float zz = sigmoidf_(gx[(size_t)r * G3 + H_N + c] + b_hh[H_N + c]);
    const float nn = tanhf(gx[(size_t)r * G3 + 2 * H_N + c] + rr * b_hh[2 * H_N + c]);
    const float hf = (1.0f - zz) * nn;
    const _Float16 hh = (_Float16)hf;
    h_hi[idx] = hh;
    h_lo[idx] = (_Float16)(hf - (float)hh);
    if (idx < B_N) {
        states[idx]           = 1.0f;
        states[B_N + idx]     = 0.0f;
        states[2 * B_N + idx] = 0.0f;
        states[3 * B_N + idx] = 0.0f;
    }
}

// ---------------- halt for n=1 (reads h0 directly) --------------------------
__global__ __launch_bounds__(256)
void halt_kernel(const int n,
                 const _Float16* __restrict__ h_hi, const _Float16* __restrict__ h_lo,
                 const float* __restrict__ w_out, const float* __restrict__ b_out,
                 const float* __restrict__ w_lam, const float* __restrict__ b_lam,
                 const float* __restrict__ u,
                 float* __restrict__ states,
                 float* __restrict__ out_p, float* __restrict__ out_y,
                 float* __restrict__ out_pm, float* __restrict__ out_ym)
{
    const int row = blockIdx.x;
    const int tid = threadIdx.x;
    const size_t base = (size_t)row * H_N + (tid << 2);
    const f16x4v hh4 = *(const f16x4v*)&h_hi[base];
    const f16x4v hl4 = *(const f16x4v*)&h_lo[base];
    const float4 wl = *(const float4*)&w_lam[tid << 2];
    const float4 wo = *(const float4*)&w_out[tid << 2];
    float hv[4];
    #pragma unroll
    for (int e = 0; e < 4; ++e) hv[e] = (float)hh4[e] + (float)hl4[e];
    float s_lam = hv[0] * wl.x + hv[1] * wl.y + hv[2] * wl.z + hv[3] * wl.w;
    float s_out = hv[0] * wo.x + hv[1] * wo.y + hv[2] * wo.z + hv[3] * wo.w;
    #pragma unroll
    for (int off = 32; off > 0; off >>= 1) {
        s_lam += __shfl_down(s_lam, off);
        s_out += __shfl_down(s_out, off);
    }
    __shared__ float redl[4], redo[4];
    const int wid = tid >> 6;
    if ((tid & 63) == 0) { redl[wid] = s_lam; redo[wid] = s_out; }
    __syncthreads();
    if (tid == 0) {
        const float dlam = redl[0] + redl[1] + redl[2] + redl[3];
        const float dout = redo[0] + redo[1] + redo[2] + redo[3];
        const float lam = (n == NSTEPS) ? 1.0f : sigmoidf_(dlam + b_lam[0]);
        const float y_n = dout + b_out[0];
        float un = states[row];
        float ha = states[B_N + row];
        float pm = states[2 * B_N + row];
        float ym = states[3 * B_N + row];
        const float p_n = un * lam;
        un = un * (1.0f - lam);
        const float halt = (u[(size_t)(n - 1) * B_N + row] < lam ? 1.0f : 0.0f) * (1.0f - ha);
        pm = pm * (1.0f - halt) + p_n * halt;
        ym = ym * (1.0f - halt) + y_n * halt;
        ha += halt;
        states[row] = un;
        states[B_N + row] = ha;
        states[2 * B_N + row] = pm;
        states[3 * B_N + row] = ym;
        out_p[(size_t)(n - 1) * B_N + row] = p_n;
        out_y[(size_t)(n - 1) * B_N + row] = y_n;
        if (n == NSTEPS) { out_pm[row] = pm; out_ym[row] = ym; }
    }
}

// ---------------- halt for n>=2: sum fused partials + state update ----------
__global__ __launch_bounds__(256)
void finish_halt_kernel(const int n,
                        const float* __restrict__ part_lam,
                        const float* __restrict__ part_out,
                        const float* __restrict__ b_out, const float* __restrict__ b_lam,
                        const float* __restrict__ u,
                        float* __restrict__ states,
                        float* __restrict__ out_p, float* __restrict__ out_y,
                        float* __restrict__ out_pm, float* __restrict__ out_ym)
{
    const int row = blockIdx.x * 256 + threadIdx.x;   // 0..B-1
    float dlam = 0.f, dout = 0.f;
    #pragma unroll
    for (int cb = 0; cb < NCB; ++cb) {                // fixed order: deterministic
        dlam += part_lam[(size_t)cb * B_N + row];
        dout += part_out[(size_t)cb * B_N + row];
    }
    const float lam = (n == NSTEPS) ? 1.0f : sigmoidf_(dlam + b_lam[0]);
    const float y_n = dout + b_out[0];
    float un = states[row];
    float ha = states[B_N + row];
    float pm = states[2 * B_N + row];
    float ym = states[3 * B_N + row];
    const float p_n = un * lam;
    un = un * (1.0f - lam);
    const float halt = (u[(size_t)(n - 1) * B_N + row] < lam ? 1.0f : 0.0f) * (1.0f - ha);
    pm = pm * (1.0f - halt) + p_n * halt;
    ym = ym * (1.0f - halt) + y_n * halt;
    ha += halt;
    states[row] = un;
    states[B_N + row] = ha;
    states[2 * B_N + row] = pm;
    states[3 * B_N + row] = ym;
    out_p[(size_t)(n - 1) * B_N + row] = p_n;
    out_y[(size_t)(n - 1) * B_N + row] = y_n;
    if (n == NSTEPS) { out_pm[row] = pm; out_ym[row] = ym; }
}

extern "C" void kernel_launch(void* const* d_in, const int* in_sizes, int n_in,
                              void* d_out, int out_size, void* d_ws, size_t ws_size,
                              hipStream_t stream) {
    const float* x     = (const float*)d_in[0];
    const float* W_ih  = (const float*)d_in[1];
    const float* W_hh  = (const float*)d_in[2];
    const float* b_ih  = (const float*)d_in[3];
    const float* b_hh  = (const float*)d_in[4];
    const float* w_out = (const float*)d_in[5];
    const float* b_out = (const float*)d_in[6];
    const float* w_lam = (const float*)d_in[7];
    const float* b_lam = (const float*)d_in[8];
    const float* u     = (const float*)d_in[9];

    float* out_p  = (float*)d_out;
    float* out_y  = out_p + (size_t)NSTEPS * B_N;
    float* out_pm = out_y + (size_t)NSTEPS * B_N;
    float* out_ym = out_pm + B_N;

    float* ws = (float*)d_ws;
    float*     gx   = ws;                                    // B*3H f32
    _Float16*  Whi  = (_Float16*)(gx + (size_t)B_N * G3);    // 3H*H f16
    _Float16*  Wlo  = Whi + (size_t)G3 * H_N;
    _Float16*  hAhi = Wlo + (size_t)G3 * H_N;                // B*H f16
    _Float16*  hAlo = hAhi + (size_t)B_N * H_N;
    _Float16*  hBhi = hAlo + (size_t)B_N * H_N;
    _Float16*  hBlo = hBhi + (size_t)B_N * H_N;
    float*     part_lam = (float*)(hBlo + (size_t)B_N * H_N); // NCB*B f32
    float*     part_out = part_lam + (size_t)NCB * B_N;
    float*     states   = part_out + (size_t)NCB * B_N;       // 4*B f32

    const dim3 blk(256);
    // one-time splits (x -> hB*, W_ih -> hA*: buffers not yet live)
    split_f32_kernel<<<dim3((size_t)G3 * H_N / 1024), blk, 0, stream>>>(W_hh, Whi, Wlo);
    split_f32_kernel<<<dim3((size_t)G3 * E_N / 1024), blk, 0, stream>>>(W_ih, hAhi, hAlo);
    split_f32_kernel<<<dim3((size_t)B_N * E_N / 1024), blk, 0, stream>>>(x, hBhi, hBlo);
    gemm_gx_mfma<<<dim3(G3 / 64, B_N / 128), blk, 0, stream>>>(hBhi, hBlo, hAhi, hAlo, b_ih, gx);
    init_h0_kernel<<<dim3(B_N * H_N / 256), blk, 0, stream>>>(gx, b_hh, hAhi, hAlo, states);

    _Float16 *hchi = hAhi, *hclo = hAlo, *hnhi = hBhi, *hnlo = hBlo;
    for (int n = 1; n <= NSTEPS; ++n) {
        if (n == 1) {
            halt_kernel<<<dim3(B_N), blk, 0, stream>>>(n, hchi, hclo, w_out, b_out,
                                                       w_lam, b_lam, u, states,
                                                       out_p, out_y, out_pm, out_ym);
        } else {
            finish_halt_kernel<<<dim3(B_N / 256), blk, 0, stream>>>(n, part_lam, part_out,
                                                                    b_out, b_lam, u, states,
                                                                    out_p, out_y, out_pm, out_ym);
        }
        if (n < NSTEPS) {
            gemm_step_mfma<<<dim3(H_N / 32, B_N / 128), blk, 0, stream>>>(
                hchi, hclo, Whi, Wlo, b_hh, gx, w_lam, w_out, hnhi, hnlo, part_lam, part_out);
            _Float16* t;
            t = hchi; hchi = hnhi; hnhi = t;
            t = hclo; hclo = hnlo; hnlo = t;
        }
    }
}

// Round 5
// 1279.904 us; speedup vs baseline: 1.0051x; 1.0051x over previous
//
#include <hip/hip_runtime.h>
#include <math.h>

// ParityPonderGRU — counted-vmcnt DEPTH-3 pipelined split-fp16 MFMA step GEMM.
// B=2048, E=512, H=1024, 20 ponder steps.
// ws: gx f32[B*3H] | Whi/Wlo f16[3H*H] | hAhi hAlo hBhi hBlo f16[B*H] |
//     part_lam f32[16*B] | part_out f32[16*B] | states f32[4*B]

#define B_N 2048
#define E_N 512
#define H_N 1024
#define G3  3072
#define NSTEPS 20
#define BK 32
#define NT_H (H_N / BK)   // 32 K-steps (step GEMM)
#define NT_E (E_N / BK)   // 16 K-steps (gx GEMM)
#define NCB  (H_N / 64)   // 16 col-blocks -> halt partials

typedef __attribute__((ext_vector_type(8))) _Float16 f16x8;
typedef __attribute__((ext_vector_type(4))) _Float16 f16x4v;
typedef __attribute__((ext_vector_type(4))) float    f32x4;

#define GLDS(src, dst) \
  __builtin_amdgcn_global_load_lds( \
      (const __attribute__((address_space(1))) void*)(src), \
      (__attribute__((address_space(3))) void*)(dst), 16, 0, 0)

__device__ __forceinline__ float sigmoidf_(float x) { return 1.0f / (1.0f + expf(-x)); }

// ---------------- Fused step GEMM: gh = h @ W_hh^T (3-product split-fp16 MFMA)
// Block 128(B) x 64(H) x 3 gates; 8 waves (2 row x 4 col); wave tile 64x16/gate.
// LDS ring: 3 slots x 20480 halves (40 KB): Ahi[0,4096) Alo[4096,8192)
// Bhi[8192,14336) Blo[14336,20480). Rows are 32 halves (64 B), lane-linear for
// global_load_lds; 16B-slot XOR-swizzled by (row&3) via pre-swizzled source.
// Schedule per tile t: vmcnt(5) -> s_barrier -> issue t+2 -> ds_read+MFMA t.
__global__ __launch_bounds__(512, 2)
void gemm_step_mfma(const _Float16* __restrict__ h_hi_in,  // [B,H]
                    const _Float16* __restrict__ h_lo_in,  // [B,H]
                    const _Float16* __restrict__ Whi,      // [3H,H]
                    const _Float16* __restrict__ Wlo,      // [3H,H]
                    const float* __restrict__ b_hh,        // [3H]
                    const float* __restrict__ gx,          // [B,3H]
                    const float* __restrict__ w_lam,
                    const float* __restrict__ w_out,
                    _Float16* __restrict__ h_hi_out,
                    _Float16* __restrict__ h_lo_out,
                    float* __restrict__ part_lam,          // [NCB*B]
                    float* __restrict__ part_out)          // [NCB*B]
{
  __shared__ _Float16 lds[3][20480];          // 122880 B
  __shared__ float pl_red[128][4], po_red[128][4];   // 4 KB

  const int tid  = threadIdx.x;
  const int lane = tid & 63;
  const int wv   = tid >> 6;     // 0..7
  const int wr   = wv >> 2;      // 0..1 row half
  const int wc   = wv & 3;       // 0..3 col quarter (16 cols)
  const int row0 = blockIdx.y * 128;   // over B
  const int col0 = blockIdx.x * 64;    // over H
  const int cb   = blockIdx.x;         // 0..15

  // staging: 40 chunks of 1 KB (16 rows x 32 halves); wave owns 5.
  // Source 16B-slot pre-swizzled: s' = seg16 ^ (row16 & 3)  (rule #21 both-sides)
  const _Float16* srcp[5];
  int ldsoff[5];
  #pragma unroll
  for (int j = 0; j < 5; ++j) {
    const int c     = wv * 5 + j;
    const int row16 = lane >> 2;
    const int seg16 = lane & 3;
    const int seg   = (seg16 ^ (row16 & 3)) * 8;   // halves
    const _Float16* s;
    if (c < 8) {
      s = h_hi_in + (size_t)(row0 + c * 16 + row16) * H_N + seg;
    } else if (c < 16) {
      s = h_lo_in + (size_t)(row0 + (c - 8) * 16 + row16) * H_N + seg;
    } else if (c < 28) {
      const int br = (c - 16) * 16 + row16;               // 0..191 (3 gates x 64)
      s = Whi + (size_t)((br >> 6) * H_N + col0 + (br & 63)) * H_N + seg;
    } else {
      const int br = (c - 28) * 16 + row16;
      s = Wlo + (size_t)((br >> 6) * H_N + col0 + (br & 63)) * H_N + seg;
    }
    srcp[j]   = s;
    ldsoff[j] = c * 512;
  }

  f32x4 acc[3][4];
  #pragma unroll
  for (int g = 0; g < 3; ++g)
    #pragma unroll
    for (int mi = 0; mi < 4; ++mi)
      acc[g][mi] = (f32x4){0.f, 0.f, 0.f, 0.f};

  const int lrow = lane & 15;
  const int q    = lane >> 4;
  const int lkp  = (q ^ (lrow & 3)) * 8;   // swizzled 16B-slot, in halves
  const int capT = 2 * cb + (wc >> 1);     // tile whose A-slice holds this thread's hold
  float hold[4][4];

  auto issue = [&](int slot) {
    #pragma unroll
    for (int j = 0; j < 5; ++j) { GLDS(srcp[j], &lds[slot][ldsoff[j]]); srcp[j] += BK; }
  };

  auto body = [&](int t, bool do_issue) {
    __builtin_amdgcn_s_barrier();
    __builtin_amdgcn_sched_barrier(0);
    if (do_issue) issue((t + 2) % 3);
    const int sl = t % 3;
    f16x8 ah[4], al[4];
    #pragma unroll
    for (int mi = 0; mi < 4; ++mi) {
      const int r = wr * 64 + mi * 16 + lrow;
      ah[mi] = *(const f16x8*)&lds[sl][r * 32 + lkp];
      al[mi] = *(const f16x8*)&lds[sl][4096 + r * 32 + lkp];
    }
    f16x8 bh[3], bl[3];
    #pragma unroll
    for (int g = 0; g < 3; ++g) {
      const int br = g * 64 + wc * 16 + lrow;
      bh[g] = *(const f16x8*)&lds[sl][8192 + br * 32 + lkp];
      bl[g] = *(const f16x8*)&lds[sl][14336 + br * 32 + lkp];
    }
    if (t == capT) {   // capture hold = h_in[m][n] from the A-tile in LDS
      #pragma unroll
      for (int mi = 0; mi < 4; ++mi)
        #pragma unroll
        for (int r = 0; r < 4; ++r) {
          const int arow = wr * 64 + mi * 16 + q * 4 + r;
          const int sslt = (((wc & 1) * 2 + (lrow >> 3)) ^ r) * 8 + (lrow & 7);
          hold[mi][r] = (float)lds[sl][arow * 32 + sslt]
                      + (float)lds[sl][4096 + arow * 32 + sslt];
        }
    }
    #pragma unroll
    for (int g = 0; g < 3; ++g)
      #pragma unroll
      for (int mi = 0; mi < 4; ++mi) {
        f32x4 c = acc[g][mi];
        c = __builtin_amdgcn_mfma_f32_16x16x32_f16(ah[mi], bh[g], c, 0, 0, 0);
        c = __builtin_amdgcn_mfma_f32_16x16x32_f16(ah[mi], bl[g], c, 0, 0, 0);
        c = __builtin_amdgcn_mfma_f32_16x16x32_f16(al[mi], bh[g], c, 0, 0, 0);
        acc[g][mi] = c;
      }
  };

  // prologue: stage tiles 0,1
  issue(0);
  issue(1);
  for (int t = 0; t < NT_H - 1; ++t) {
    asm volatile("s_waitcnt vmcnt(5)" ::: "memory");   // tile t done; t+1 in flight
    body(t, t < NT_H - 2);
  }
  asm volatile("s_waitcnt vmcnt(0)" ::: "memory");     // last tile
  body(NT_H - 1, false);

  // Epilogue: D frag col=lane&15 (n), row=(lane>>4)*4+r (m)  [m89]
  const int n   = col0 + wc * 16 + lrow;
  const float bhr = b_hh[n];
  const float bhz = b_hh[H_N + n];
  const float bhn = b_hh[2 * H_N + n];
  const float wl  = w_lam[n];
  const float wo  = w_out[n];
  #pragma unroll
  for (int mi = 0; mi < 4; ++mi) {
    #pragma unroll
    for (int r = 0; r < 4; ++r) {
      const int m = row0 + wr * 64 + mi * 16 + q * 4 + r;
      const float gr = acc[0][mi][r] + bhr;
      const float gz = acc[1][mi][r] + bhz;
      const float gn = acc[2][mi][r] + bhn;
      const size_t gxb = (size_t)m * G3;
      const float rr = sigmoidf_(gx[gxb + n] + gr);
      const float zz = sigmoidf_(gx[gxb + H_N + n] + gz);
      const float nn = tanhf(gx[gxb + 2 * H_N + n] + rr * gn);
      const float hf = (1.f - zz) * nn + zz * hold[mi][r];
      const _Float16 hh = (_Float16)hf;
      const size_t hidx = (size_t)m * H_N + n;
      h_hi_out[hidx] = hh;
      h_lo_out[hidx] = (_Float16)(hf - (float)hh);
      float pl = hf * wl;
      float po = hf * wo;
      #pragma unroll
      for (int mk = 1; mk < 16; mk <<= 1) {
        pl += __shfl_xor(pl, mk);
        po += __shfl_xor(po, mk);
      }
      if (lrow == 0) {
        pl_red[wr * 64 + mi * 16 + q * 4 + r][wc] = pl;
        po_red[wr * 64 + mi * 16 + q * 4 + r][wc] = po;
      }
    }
  }
  __syncthreads();
  if (tid < 128) {
    const int m = row0 + tid;
    part_lam[(size_t)cb * B_N + m] = (pl_red[tid][0] + pl_red[tid][1])
                                   + (pl_red[tid][2] + pl_red[tid][3]);
    part_out[(size_t)cb * B_N + m] = (po_red[tid][0] + po_red[tid][1])
                                   + (po_red[tid][2] + po_red[tid][3]);
  }
}

// ---------------- gx GEMM (MFMA): gx = x @ W_ih^T + b_ih -------------------
__global__ __launch_bounds__(256, 3)
void gemm_gx_mfma(const _Float16* __restrict__ xhi,    // [B,E]
                  const _Float16* __restrict__ xlo,
                  const _Float16* __restrict__ Wihhi,  // [3H,E]
                  const _Float16* __restrict__ Wihlo,
                  const float* __restrict__ b_ih,
                  float* __restrict__ gx)              // [B,3H]
{
  __shared__ _Float16 lds[2][12288];   // 49152 B

  const int tid  = threadIdx.x;
  const int lane = tid & 63;
  const int wv   = tid >> 6;
  const int wr   = wv >> 1;
  const int wc   = wv & 1;
  const int row0 = blockIdx.y * 128;   // over B
  const int col0 = blockIdx.x * 64;    // over 3H

  const _Float16* srcp[6];
  int ldsoff[6];
  #pragma unroll
  for (int j = 0; j < 6; ++j) {
    const int c     = wv * 6 + j;
    const int seg   = (lane & 3) * 8;
    const int row16 = lane >> 2;
    const _Float16* s;
    if (c < 8)       s = xhi   + (size_t)(row0 + c * 16 + row16) * E_N + seg;
    else if (c < 16) s = xlo   + (size_t)(row0 + (c - 8) * 16 + row16) * E_N + seg;
    else if (c < 20) s = Wihhi + (size_t)(col0 + (c - 16) * 16 + row16) * E_N + seg;
    else             s = Wihlo + (size_t)(col0 + (c - 20) * 16 + row16) * E_N + seg;
    srcp[j]   = s;
    ldsoff[j] = c * 512;
  }

  f32x4 acc[4][2];
  #pragma unroll
  for (int mi = 0; mi < 4; ++mi)
    #pragma unroll
    for (int ni = 0; ni < 2; ++ni) acc[mi][ni] = (f32x4){0.f, 0.f, 0.f, 0.f};

  const int lrow = lane & 15;
  const int lk   = (lane >> 4) * 8;
  const int q    = lane >> 4;

  #pragma unroll
  for (int j = 0; j < 6; ++j) { GLDS(srcp[j], &lds[0][ldsoff[j]]); srcp[j] += BK; }
  __syncthreads();

  for (int t = 0; t < NT_E; ++t) {
    const int p = t & 1;
    if (t + 1 < NT_E) {
      #pragma unroll
      for (int j = 0; j < 6; ++j) { GLDS(srcp[j], &lds[p ^ 1][ldsoff[j]]); srcp[j] += BK; }
    }
    f16x8 ah[4], al[4];
    #pragma unroll
    for (int mi = 0; mi < 4; ++mi) {
      const int r = wr * 64 + mi * 16 + lrow;
      ah[mi] = *(const f16x8*)&lds[p][r * 32 + lk];
      al[mi] = *(const f16x8*)&lds[p][4096 + r * 32 + lk];
    }
    f16x8 bh[2], bl[2];
    #pragma unroll
    for (int ni = 0; ni < 2; ++ni) {
      const int r = wc * 32 + ni * 16 + lrow;
      bh[ni] = *(const f16x8*)&lds[p][8192 + r * 32 + lk];
      bl[ni] = *(const f16x8*)&lds[p][10240 + r * 32 + lk];
    }
    #pragma unroll
    for (int mi = 0; mi < 4; ++mi)
      #pragma unroll
      for (int ni = 0; ni < 2; ++ni) {
        f32x4 c = acc[mi][ni];
        c = __builtin_amdgcn_mfma_f32_16x16x32_f16(ah[mi], bh[ni], c, 0, 0, 0);
        c = __builtin_amdgcn_mfma_f32_16x16x32_f16(ah[mi], bl[ni], c, 0, 0, 0);
        c = __builtin_amdgcn_mfma_f32_16x16x32_f16(al[mi], bh[ni], c, 0, 0, 0);
        acc[mi][ni] = c;
      }
    __syncthreads();
  }

  #pragma unroll
  for (int mi = 0; mi < 4; ++mi) {
    #pragma unroll
    for (int ni = 0; ni < 2; ++ni) {
      const int n = col0 + wc * 32 + ni * 16 + lrow;
      const float bi = b_ih[n];
      #pragma unroll
      for (int r = 0; r < 4; ++r) {
        const int m = row0 + wr * 64 + mi * 16 + q * 4 + r;
        gx[(size_t)m * G3 + n] = acc[mi][ni][r] + bi;
      }
    }
  }
}

// ---------------- one-time: split fp32 -> fp16 hi/lo -----------------------
__global__ __launch_bounds__(256)
void split_f32_kernel(const float* __restrict__ src,
                      _Float16* __restrict__ hi, _Float16* __restrict__ lo)
{
  const size_t base = ((size_t)blockIdx.x * 256 + threadIdx.x) * 4;
  const float4 w = *(const float4*)&src[base];
  float s[4] = {w.x, w.y, w.z, w.w};
  f16x4v h4, l4;
  #pragma unroll
  for (int e = 0; e < 4; ++e) {
    const _Float16 h = (_Float16)s[e];
    h4[e] = h;
    l4[e] = (_Float16)(s[e] - (float)h);
  }
  *(f16x4v*)&hi[base] = h4;
  *(f16x4v*)&lo[base] = l4;
}

// ---------------- h0 = gru_cell(x, 0): gh = b_hh; init states --------------
__global__ __launch_bounds__(256)
void init_h0_kernel(const float* __restrict__ gx, const float* __restrict__ b_hh,
                    _Float16* __restrict__ h_hi, _Float16* __restrict__ h_lo,
                    float* __restrict__ states)
{
    const int idx = blockIdx.x * 256 + threadIdx.x;
    const int r = idx >> 10;
    const int c = idx & (H_N - 1);
    const float rr = sigmoidf_(gx[(size_t)r * G3 + c] + b_hh[c]);
    const float zz = sigmoidf_(gx[(size_t)r * G3 + H_N + c] + b_hh[H_N + c]);
    const float nn = tanhf(gx[(size_t)r * G3 + 2 * H_N + c] + rr * b_hh[2 * H_N + c]);
    const float hf = (1.0f - zz) * nn;
    const _Float16 hh = (_Float16)hf;
    h_hi[idx] = hh;
    h_lo[idx] = (_Float16)(hf - (float)hh);
    if (idx < B_N) {
        states[idx]           = 1.0f;
        states[B_N + idx]     = 0.0f;
        states[2 * B_N + idx] = 0.0f;
        states[3 * B_N + idx] = 0.0f;
    }
}

// ---------------- halt for n=1 (reads h0 directly) --------------------------
__global__ __launch_bounds__(256)
void halt_kernel(const int n,
                 const _Float16* __restrict__ h_hi, const _Float16* __restrict__ h_lo,
                 const float* __restrict__ w_out, const float* __restrict__ b_out,
                 const float* __restrict__ w_lam, const float* __restrict__ b_lam,
                 const float* __restrict__ u,
                 float* __restrict__ states,
                 float* __restrict__ out_p, float* __restrict__ out_y,
                 float* __restrict__ out_pm, float* __restrict__ out_ym)
{
    const int row = blockIdx.x;
    const int tid = threadIdx.x;
    const size_t base = (size_t)row * H_N + (tid << 2);
    const f16x4v hh4 = *(const f16x4v*)&h_hi[base];
    const f16x4v hl4 = *(const f16x4v*)&h_lo[base];
    const float4 wl = *(const float4*)&w_lam[tid << 2];
    const float4 wo = *(const float4*)&w_out[tid << 2];
    float hv[4];
    #pragma unroll
    for (int e = 0; e < 4; ++e) hv[e] = (float)hh4[e] + (float)hl4[e];
    float s_lam = hv[0] * wl.x + hv[1] * wl.y + hv[2] * wl.z + hv[3] * wl.w;
    float s_out = hv[0] * wo.x + hv[1] * wo.y + hv[2] * wo.z + hv[3] * wo.w;
    #pragma unroll
    for (int off = 32; off > 0; off >>= 1) {
        s_lam += __shfl_down(s_lam, off);
        s_out += __shfl_down(s_out, off);
    }
    __shared__ float redl[4], redo[4];
    const int wid = tid >> 6;
    if ((tid & 63) == 0) { redl[wid] = s_lam; redo[wid] = s_out; }
    __syncthreads();
    if (tid == 0) {
        const float dlam = redl[0] + redl[1] + redl[2] + redl[3];
        const float dout = redo[0] + redo[1] + redo[2] + redo[3];
        const float lam = (n == NSTEPS) ? 1.0f : sigmoidf_(dlam + b_lam[0]);
        const float y_n = dout + b_out[0];
        float un = states[row];
        float ha = states[B_N + row];
        float pm = states[2 * B_N + row];
        float ym = states[3 * B_N + row];
        const float p_n = un * lam;
        un = un * (1.0f - lam);
        const float halt = (u[(size_t)(n - 1) * B_N + row] < lam ? 1.0f : 0.0f) * (1.0f - ha);
        pm = pm * (1.0f - halt) + p_n * halt;
        ym = ym * (1.0f - halt) + y_n * halt;
        ha += halt;
        states[row] = un;
        states[B_N + row] = ha;
        states[2 * B_N + row] = pm;
        states[3 * B_N + row] = ym;
        out_p[(size_t)(n - 1) * B_N + row] = p_n;
        out_y[(size_t)(n - 1) * B_N + row] = y_n;
        if (n == NSTEPS) { out_pm[row] = pm; out_ym[row] = ym; }
    }
}

// ---------------- halt for n>=2: sum fused partials + state update ----------
__global__ __launch_bounds__(256)
void finish_halt_kernel(const int n,
                        const float* __restrict__ part_lam,
                        const float* __restrict__ part_out,
                        const float* __restrict__ b_out, const float* __restrict__ b_lam,
                        const float* __restrict__ u,
                        float* __restrict__ states,
                        float* __restrict__ out_p, float* __restrict__ out_y,
                        float* __restrict__ out_pm, float* __restrict__ out_ym)
{
    const int row = blockIdx.x * 256 + threadIdx.x;   // 0..B-1
    float dlam = 0.f, dout = 0.f;
    #pragma unroll
    for (int cb = 0; cb < NCB; ++cb) {                // fixed order: deterministic
        dlam += part_lam[(size_t)cb * B_N + row];
        dout += part_out[(size_t)cb * B_N + row];
    }
    const float lam = (n == NSTEPS) ? 1.0f : sigmoidf_(dlam + b_lam[0]);
    const float y_n = dout + b_out[0];
    float un = states[row];
    float ha = states[B_N + row];
    float pm = states[2 * B_N + row];
    float ym = states[3 * B_N + row];
    const float p_n = un * lam;
    un = un * (1.0f - lam);
    const float halt = (u[(size_t)(n - 1) * B_N + row] < lam ? 1.0f : 0.0f) * (1.0f - ha);
    pm = pm * (1.0f - halt) + p_n * halt;
    ym = ym * (1.0f - halt) + y_n * halt;
    ha += halt;
    states[row] = un;
    states[B_N + row] = ha;
    states[2 * B_N + row] = pm;
    states[3 * B_N + row] = ym;
    out_p[(size_t)(n - 1) * B_N + row] = p_n;
    out_y[(size_t)(n - 1) * B_N + row] = y_n;
    if (n == NSTEPS) { out_pm[row] = pm; out_ym[row] = ym; }
}

extern "C" void kernel_launch(void* const* d_in, const int* in_sizes, int n_in,
                              void* d_out, int out_size, void* d_ws, size_t ws_size,
                              hipStream_t stream) {
    const float* x     = (const float*)d_in[0];
    const float* W_ih  = (const float*)d_in[1];
    const float* W_hh  = (const float*)d_in[2];
    const float* b_ih  = (const float*)d_in[3];
    const float* b_hh  = (const float*)d_in[4];
    const float* w_out = (const float*)d_in[5];
    const float* b_out = (const float*)d_in[6];
    const float* w_lam = (const float*)d_in[7];
    const float* b_lam = (const float*)d_in[8];
    const float* u     = (const float*)d_in[9];

    float* out_p  = (float*)d_out;
    float* out_y  = out_p + (size_t)NSTEPS * B_N;
    float* out_pm = out_y + (size_t)NSTEPS * B_N;
    float* out_ym = out_pm + B_N;

    float* ws = (float*)d_ws;
    float*     gx   = ws;                                    // B*3H f32
    _Float16*  Whi  = (_Float16*)(gx + (size_t)B_N * G3);    // 3H*H f16
    _Float16*  Wlo  = Whi + (size_t)G3 * H_N;
    _Float16*  hAhi = Wlo + (size_t)G3 * H_N;                // B*H f16
    _Float16*  hAlo = hAhi + (size_t)B_N * H_N;
    _Float16*  hBhi = hAlo + (size_t)B_N * H_N;
    _Float16*  hBlo = hBhi + (size_t)B_N * H_N;
    float*     part_lam = (float*)(hBlo + (size_t)B_N * H_N); // NCB*B f32
    float*     part_out = part_lam + (size_t)NCB * B_N;
    float*     states   = part_out + (size_t)NCB * B_N;       // 4*B f32

    const dim3 blk(256);
    split_f32_kernel<<<dim3((size_t)G3 * H_N / 1024), blk, 0, stream>>>(W_hh, Whi, Wlo);
    split_f32_kernel<<<dim3((size_t)G3 * E_N / 1024), blk, 0, stream>>>(W_ih, hAhi, hAlo);
    split_f32_kernel<<<dim3((size_t)B_N * E_N / 1024), blk, 0, stream>>>(x, hBhi, hBlo);
    gemm_gx_mfma<<<dim3(G3 / 64, B_N / 128), blk, 0, stream>>>(hBhi, hBlo, hAhi, hAlo, b_ih, gx);
    init_h0_kernel<<<dim3(B_N * H_N / 256), blk, 0, stream>>>(gx, b_hh, hAhi, hAlo, states);

    _Float16 *hchi = hAhi, *hclo = hAlo, *hnhi = hBhi, *hnlo = hBlo;
    for (int n = 1; n <= NSTEPS; ++n) {
        if (n == 1) {
            halt_kernel<<<dim3(B_N), blk, 0, stream>>>(n, hchi, hclo, w_out, b_out,
                                                       w_lam, b_lam, u, states,
                                                       out_p, out_y, out_pm, out_ym);
        } else {
            finish_halt_kernel<<<dim3(B_N / 256), blk, 0, stream>>>(n, part_lam, part_out,
                                                                    b_out, b_lam, u, states,
                                                                    out_p, out_y, out_pm, out_ym);
        }
        if (n < NSTEPS) {
            gemm_step_mfma<<<dim3(H_N / 64, B_N / 128), dim3(512), 0, stream>>>(
                hchi, hclo, Whi, Wlo, b_hh, gx, w_lam, w_out, hnhi, hnlo, part_lam, part_out);
            _Float16* t;
            t = hchi; hchi = hnhi; hnhi = t;
            t = hclo; hclo = hnlo; hnlo = t;
        }
    }
}